// Round 3
// baseline (41.372 us; speedup 1.0000x reference)
//
#include <hip/hip_runtime.h>
#include <math.h>

// Bundle-adjustment edge reprojection, round 3:
//  - poses repacked 7f -> 2x float4 (aligned gathers, 256 KB in d_ws)
//  - 2 edges per thread, vectorized coalesced loads/stores
//  - fast atan2 polynomial (abs err ~1e-4, threshold is 1.48)
//  (nontemporal builtins removed: they reject HIP_vector_type pointers)

#define POSE_NUM 8192

__global__ __launch_bounds__(256) void repack_poses_kernel(
    const float* __restrict__ poses,  // [8192*7]
    float4* __restrict__ pose8)       // [8192*2]
{
    int i = blockIdx.x * blockDim.x + threadIdx.x;
    if (i >= POSE_NUM) return;
    const float* p = poses + i * 7;
    pose8[i * 2 + 0] = make_float4(p[0], p[1], p[2], p[3]);  // t.xyz, qx
    pose8[i * 2 + 1] = make_float4(p[4], p[5], p[6], 0.0f);  // qy, qz, qw
}

__device__ __forceinline__ float fast_atan2f(float y, float x) {
    float ax = fabsf(x), ay = fabsf(y);
    float mx = fmaxf(ax, ay), mn = fminf(ax, ay);
    float t = mn * __builtin_amdgcn_rcpf(fmaxf(mx, 1e-30f));
    float s = t * t;
    // minimax poly for atan(t), t in [0,1]
    float r = fmaf(s, fmaf(s, fmaf(s, fmaf(s, 0.0208351f, -0.0851330f),
                                   0.1801410f), -0.3302995f), 0.9998660f) * t;
    if (ay > ax) r = 1.5707963267948966f - r;
    if (x < 0.0f) r = 3.14159265358979f - r;
    return y < 0.0f ? -r : r;
}

__device__ __forceinline__ void edge_compute(
    int pi, int ki,
    const float2* __restrict__ patch_coords,
    const float*  __restrict__ elev,
    const float4* __restrict__ pose8,
    float tgx, float tgy, float* ox, float* oy)
{
    const float2 rt  = patch_coords[ki];
    const float  phi = elev[ki];
    const float  r = rt.x, theta = rt.y;

    float sphi, cphi, st, ct;
    __sincosf(phi,   &sphi, &cphi);
    __sincosf(theta, &st,   &ct);

    const float rc = r * cphi;
    const float px = rc * ct;
    const float py = rc * st;
    const float pz = r * sphi;

    const float4 pa = pose8[pi * 2 + 0];
    const float4 pb = pose8[pi * 2 + 1];
    const float tx = pa.x, ty = pa.y, tz = pa.z;
    const float qx = pa.w, qy = pb.x, qz = pb.y, qw = pb.z;

    const float ux = qy * pz - qz * py;
    const float uy = qz * px - qx * pz;
    const float uz = qx * py - qy * px;
    const float cx = qy * uz - qz * uy;
    const float cy = qz * ux - qx * uz;
    const float cz = qx * uy - qy * ux;

    const float x = px + 2.0f * (qw * ux + cx) + tx;
    const float y = py + 2.0f * (qw * uy + cy) + ty;
    const float z = pz + 2.0f * (qw * uz + cz) + tz;

    *ox = sqrtf(x * x + y * y + z * z) - tgx;
    *oy = fast_atan2f(y, x) - tgy;
}

__global__ __launch_bounds__(256) void ba_edge_kernel2(
    const float2* __restrict__ patch_coords,  // [E]
    const float*  __restrict__ elev,          // [E]
    const float2* __restrict__ target,        // [E]
    const int*    __restrict__ poses_idx,     // [E]
    const int*    __restrict__ patch_idx,     // [E]
    const float4* __restrict__ pose8,         // [8192*2]
    float4*       __restrict__ out,           // [E/2]
    int half_n)
{
    int t = blockIdx.x * blockDim.x + threadIdx.x;
    if (t >= half_n) return;

    const int2 pidx = ((const int2*)poses_idx)[t];
    const int2 kidx = ((const int2*)patch_idx)[t];
    const float4 tg = ((const float4*)target)[t];

    float4 o;
    edge_compute(pidx.x, kidx.x, patch_coords, elev, pose8, tg.x, tg.y, &o.x, &o.y);
    edge_compute(pidx.y, kidx.y, patch_coords, elev, pose8, tg.z, tg.w, &o.z, &o.w);
    out[t] = o;
}

// Fallback (ws too small or odd n): round-1 single kernel
__global__ __launch_bounds__(256) void ba_edge_kernel1(
    const float*  __restrict__ poses,
    const float2* __restrict__ patch_coords,
    const float*  __restrict__ elev,
    const float2* __restrict__ target,
    const int*    __restrict__ poses_idx,
    const int*    __restrict__ patch_idx,
    float2*       __restrict__ out,
    int n)
{
    int e = blockIdx.x * blockDim.x + threadIdx.x;
    if (e >= n) return;
    const int pi = poses_idx[e];
    const int ki = patch_idx[e];
    const float2 rt  = patch_coords[ki];
    const float  phi = elev[ki];
    float sphi, cphi, st, ct;
    __sincosf(phi, &sphi, &cphi);
    __sincosf(rt.y, &st, &ct);
    const float rc = rt.x * cphi;
    const float px = rc * ct, py = rc * st, pz = rt.x * sphi;
    const float* p = poses + pi * 7;
    const float tx = p[0], ty = p[1], tz = p[2];
    const float qx = p[3], qy = p[4], qz = p[5], qw = p[6];
    const float ux = qy * pz - qz * py;
    const float uy = qz * px - qx * pz;
    const float uz = qx * py - qy * px;
    const float cx = qy * uz - qz * uy;
    const float cy = qz * ux - qx * uz;
    const float cz = qx * uy - qy * ux;
    const float x = px + 2.0f * (qw * ux + cx) + tx;
    const float y = py + 2.0f * (qw * uy + cy) + ty;
    const float z = pz + 2.0f * (qw * uz + cz) + tz;
    const float2 tg = target[e];
    out[e] = make_float2(sqrtf(x * x + y * y + z * z) - tg.x,
                         fast_atan2f(y, x) - tg.y);
}

extern "C" void kernel_launch(void* const* d_in, const int* in_sizes, int n_in,
                              void* d_out, int out_size, void* d_ws, size_t ws_size,
                              hipStream_t stream) {
    const float*  poses        = (const float*)d_in[0];
    const float2* patch_coords = (const float2*)d_in[1];
    const float*  elev         = (const float*)d_in[2];
    const float2* target       = (const float2*)d_in[3];
    const int*    poses_idx    = (const int*)d_in[4];
    const int*    patch_idx    = (const int*)d_in[5];
    const int n = in_sizes[4];

    const size_t pose8_bytes = (size_t)POSE_NUM * 8 * sizeof(float);

    if (ws_size >= pose8_bytes && (n & 1) == 0) {
        float4* pose8 = (float4*)d_ws;
        repack_poses_kernel<<<(POSE_NUM + 255) / 256, 256, 0, stream>>>(poses, pose8);
        const int half_n = n / 2;
        ba_edge_kernel2<<<(half_n + 255) / 256, 256, 0, stream>>>(
            patch_coords, elev, target, poses_idx, patch_idx, pose8,
            (float4*)d_out, half_n);
    } else {
        ba_edge_kernel1<<<(n + 255) / 256, 256, 0, stream>>>(
            poses, patch_coords, elev, target, poses_idx, patch_idx,
            (float2*)d_out, n);
    }
}

// Round 4
// 37.068 us; speedup vs baseline: 1.1161x; 1.1161x over previous
//
#include <hip/hip_runtime.h>
#include <math.h>

// Round 4:
//  - Precompute kernel (streaming): pts[ki] = spherical->cartesian per patch
//    (fuses patch_coords + elev, moves all trig out of edge kernel),
//    plus pose 7f->2x float4 repack. One launch, writes d_ws.
//  - Edge kernel: 1 divergent float4 gather (pts) + 2 L1-resident pose
//    gathers per edge; 2 edges/thread; fast atan2 poly.

#define POSE_NUM   8192
#define PTS_BYTES  (16u * 1024u * 1024u)       // 1M float4
#define POSE8_OFF  PTS_BYTES                    // pose8 after pts table

__device__ __forceinline__ float fast_atan2f(float y, float x) {
    float ax = fabsf(x), ay = fabsf(y);
    float mx = fmaxf(ax, ay), mn = fminf(ax, ay);
    float t = mn * __builtin_amdgcn_rcpf(fmaxf(mx, 1e-30f));
    float s = t * t;
    float r = fmaf(s, fmaf(s, fmaf(s, fmaf(s, 0.0208351f, -0.0851330f),
                                   0.1801410f), -0.3302995f), 0.9998660f) * t;
    if (ay > ax) r = 1.5707963267948966f - r;
    if (x < 0.0f) r = 3.14159265358979f - r;
    return y < 0.0f ? -r : r;
}

__global__ __launch_bounds__(256) void precompute_kernel(
    const float2* __restrict__ patch_coords,  // [NP]
    const float*  __restrict__ elev,          // [NP]
    const float*  __restrict__ poses,         // [8192*7]
    float4* __restrict__ pts,                 // [NP]
    float4* __restrict__ pose8,               // [8192*2]
    int npatch)
{
    int i = blockIdx.x * blockDim.x + threadIdx.x;
    if (i < npatch) {
        const float2 rt = patch_coords[i];
        const float phi = elev[i];
        float sphi, cphi, st, ct;
        __sincosf(phi,  &sphi, &cphi);
        __sincosf(rt.y, &st,   &ct);
        const float rc = rt.x * cphi;
        pts[i] = make_float4(rc * ct, rc * st, rt.x * sphi, 0.0f);
    }
    if (i < POSE_NUM) {
        const float* p = poses + i * 7;
        pose8[i * 2 + 0] = make_float4(p[0], p[1], p[2], p[3]);  // t.xyz, qx
        pose8[i * 2 + 1] = make_float4(p[4], p[5], p[6], 0.0f);  // qy,qz,qw
    }
}

__device__ __forceinline__ void edge_finish(
    float4 P, float4 pa, float4 pb,
    float tgx, float tgy, float* ox, float* oy)
{
    const float px = P.x, py = P.y, pz = P.z;
    const float tx = pa.x, ty = pa.y, tz = pa.z;
    const float qx = pa.w, qy = pb.x, qz = pb.y, qw = pb.z;

    const float ux = qy * pz - qz * py;
    const float uy = qz * px - qx * pz;
    const float uz = qx * py - qy * px;
    const float cx = qy * uz - qz * uy;
    const float cy = qz * ux - qx * uz;
    const float cz = qx * uy - qy * ux;

    const float x = px + 2.0f * (qw * ux + cx) + tx;
    const float y = py + 2.0f * (qw * uy + cy) + ty;
    const float z = pz + 2.0f * (qw * uz + cz) + tz;

    *ox = sqrtf(x * x + y * y + z * z) - tgx;
    *oy = fast_atan2f(y, x) - tgy;
}

__global__ __launch_bounds__(256) void edge_kernel(
    const float4* __restrict__ pts,        // [NP]
    const float4* __restrict__ pose8,      // [8192*2]
    const float2* __restrict__ target,     // [E]
    const int*    __restrict__ poses_idx,  // [E]
    const int*    __restrict__ patch_idx,  // [E]
    float4*       __restrict__ out,        // [E/2]
    int half_n)
{
    int t = blockIdx.x * blockDim.x + threadIdx.x;
    if (t >= half_n) return;

    const int2 pidx = ((const int2*)poses_idx)[t];
    const int2 kidx = ((const int2*)patch_idx)[t];
    const float4 tg = ((const float4*)target)[t];

    // issue all gathers before consuming (let them overlap)
    const float4 P0 = pts[kidx.x];
    const float4 P1 = pts[kidx.y];
    const float4 a0 = pose8[2 * pidx.x + 0];
    const float4 b0 = pose8[2 * pidx.x + 1];
    const float4 a1 = pose8[2 * pidx.y + 0];
    const float4 b1 = pose8[2 * pidx.y + 1];

    float4 o;
    edge_finish(P0, a0, b0, tg.x, tg.y, &o.x, &o.y);
    edge_finish(P1, a1, b1, tg.z, tg.w, &o.z, &o.w);
    out[t] = o;
}

// Fallback (ws too small or odd n): round-1 style single kernel
__global__ __launch_bounds__(256) void ba_edge_kernel1(
    const float*  __restrict__ poses,
    const float2* __restrict__ patch_coords,
    const float*  __restrict__ elev,
    const float2* __restrict__ target,
    const int*    __restrict__ poses_idx,
    const int*    __restrict__ patch_idx,
    float2*       __restrict__ out,
    int n)
{
    int e = blockIdx.x * blockDim.x + threadIdx.x;
    if (e >= n) return;
    const int pi = poses_idx[e];
    const int ki = patch_idx[e];
    const float2 rt  = patch_coords[ki];
    const float  phi = elev[ki];
    float sphi, cphi, st, ct;
    __sincosf(phi, &sphi, &cphi);
    __sincosf(rt.y, &st, &ct);
    const float rc = rt.x * cphi;
    const float px = rc * ct, py = rc * st, pz = rt.x * sphi;
    const float* p = poses + pi * 7;
    const float tx = p[0], ty = p[1], tz = p[2];
    const float qx = p[3], qy = p[4], qz = p[5], qw = p[6];
    const float ux = qy * pz - qz * py;
    const float uy = qz * px - qx * pz;
    const float uz = qx * py - qy * px;
    const float cx = qy * uz - qz * uy;
    const float cy = qz * ux - qx * uz;
    const float cz = qx * uy - qy * ux;
    const float x = px + 2.0f * (qw * ux + cx) + tx;
    const float y = py + 2.0f * (qw * uy + cy) + ty;
    const float z = pz + 2.0f * (qw * uz + cz) + tz;
    const float2 tg = target[e];
    out[e] = make_float2(sqrtf(x * x + y * y + z * z) - tg.x,
                         fast_atan2f(y, x) - tg.y);
}

extern "C" void kernel_launch(void* const* d_in, const int* in_sizes, int n_in,
                              void* d_out, int out_size, void* d_ws, size_t ws_size,
                              hipStream_t stream) {
    const float*  poses        = (const float*)d_in[0];
    const float2* patch_coords = (const float2*)d_in[1];
    const float*  elev         = (const float*)d_in[2];
    const float2* target       = (const float2*)d_in[3];
    const int*    poses_idx    = (const int*)d_in[4];
    const int*    patch_idx    = (const int*)d_in[5];

    const int n      = in_sizes[4];       // edges
    const int npatch = in_sizes[2];       // elevation_angle count = patch count

    const size_t need = (size_t)npatch * 16 + (size_t)POSE_NUM * 32;

    if (ws_size >= need && (n & 1) == 0 && npatch * 16u <= PTS_BYTES) {
        float4* pts   = (float4*)d_ws;
        float4* pose8 = (float4*)((char*)d_ws + POSE8_OFF);
        const int pre_grid = (npatch + 255) / 256;
        precompute_kernel<<<pre_grid, 256, 0, stream>>>(
            patch_coords, elev, poses, pts, pose8, npatch);
        const int half_n = n / 2;
        edge_kernel<<<(half_n + 255) / 256, 256, 0, stream>>>(
            pts, pose8, target, poses_idx, patch_idx, (float4*)d_out, half_n);
    } else {
        ba_edge_kernel1<<<(n + 255) / 256, 256, 0, stream>>>(
            poses, patch_coords, elev, target, poses_idx, patch_idx,
            (float2*)d_out, n);
    }
}

// Round 6
// 35.459 us; speedup vs baseline: 1.1668x; 1.0454x over previous
//
#include <hip/hip_runtime.h>
#include <math.h>

// Round 6: single kernel (no precompute — R3/R4 proved a second kernel costs
// ~5us and saves nothing), 4 edges/thread for MLP, vectorized nontemporal
// streams (idx/target/out), f32 gathers only (fp16 table failed: atan2
// branch-cut flip after translation near-cancellation).

typedef float f4 __attribute__((ext_vector_type(4)));
typedef int   i4 __attribute__((ext_vector_type(4)));

__device__ __forceinline__ float fast_atan2f(float y, float x) {
    float ax = fabsf(x), ay = fabsf(y);
    float mx = fmaxf(ax, ay), mn = fminf(ax, ay);
    float t = mn * __builtin_amdgcn_rcpf(fmaxf(mx, 1e-30f));
    float s = t * t;
    float r = fmaf(s, fmaf(s, fmaf(s, fmaf(s, 0.0208351f, -0.0851330f),
                                   0.1801410f), -0.3302995f), 0.9998660f) * t;
    if (ay > ax) r = 1.5707963267948966f - r;
    if (x < 0.0f) r = 3.14159265358979f - r;
    return y < 0.0f ? -r : r;
}

__device__ __forceinline__ void edge_body(
    float2 rt, float phi, const float* __restrict__ p,
    float tgx, float tgy, float* ox, float* oy)
{
    float sphi, cphi, st, ct;
    __sincosf(phi,  &sphi, &cphi);
    __sincosf(rt.y, &st,   &ct);
    const float rc = rt.x * cphi;
    const float px = rc * ct, py = rc * st, pz = rt.x * sphi;

    const float tx = p[0], ty = p[1], tz = p[2];
    const float qx = p[3], qy = p[4], qz = p[5], qw = p[6];

    const float ux = qy * pz - qz * py;
    const float uy = qz * px - qx * pz;
    const float uz = qx * py - qy * px;
    const float cx = qy * uz - qz * uy;
    const float cy = qz * ux - qx * uz;
    const float cz = qx * uy - qy * ux;

    const float x = px + 2.0f * (qw * ux + cx) + tx;
    const float y = py + 2.0f * (qw * uy + cy) + ty;
    const float z = pz + 2.0f * (qw * uz + cz) + tz;

    *ox = sqrtf(x * x + y * y + z * z) - tgx;
    *oy = fast_atan2f(y, x) - tgy;
}

__global__ __launch_bounds__(256) void edge_kernel4(
    const float*  __restrict__ poses,         // [8192*7]
    const float2* __restrict__ patch_coords,  // [E]
    const float*  __restrict__ elev,          // [E]
    const f4*     __restrict__ target,        // [E/2] (2 targets per f4)
    const i4*     __restrict__ poses_idx,     // [E/4]
    const i4*     __restrict__ patch_idx,     // [E/4]
    f4*           __restrict__ out,           // [E/2]
    int quarter_n)
{
    int t = blockIdx.x * blockDim.x + threadIdx.x;
    if (t >= quarter_n) return;

    const i4 pi = __builtin_nontemporal_load(poses_idx + t);
    const i4 ki = __builtin_nontemporal_load(patch_idx + t);
    const f4 tgA = __builtin_nontemporal_load(target + 2 * t);      // e0,e1
    const f4 tgB = __builtin_nontemporal_load(target + 2 * t + 1);  // e2,e3

    // Issue the slow table gathers for all 4 edges up front (MLP).
    const float2 rt0 = patch_coords[ki.x];
    const float2 rt1 = patch_coords[ki.y];
    const float2 rt2 = patch_coords[ki.z];
    const float2 rt3 = patch_coords[ki.w];
    const float  ph0 = elev[ki.x];
    const float  ph1 = elev[ki.y];
    const float  ph2 = elev[ki.z];
    const float  ph3 = elev[ki.w];

    const float* p0 = poses + pi.x * 7;
    const float* p1 = poses + pi.y * 7;
    const float* p2 = poses + pi.z * 7;
    const float* p3 = poses + pi.w * 7;

    f4 oA, oB;
    float a, b;
    edge_body(rt0, ph0, p0, tgA.x, tgA.y, &a, &b); oA.x = a; oA.y = b;
    edge_body(rt1, ph1, p1, tgA.z, tgA.w, &a, &b); oA.z = a; oA.w = b;
    edge_body(rt2, ph2, p2, tgB.x, tgB.y, &a, &b); oB.x = a; oB.y = b;
    edge_body(rt3, ph3, p3, tgB.z, tgB.w, &a, &b); oB.z = a; oB.w = b;

    __builtin_nontemporal_store(oA, out + 2 * t);
    __builtin_nontemporal_store(oB, out + 2 * t + 1);
}

// Fallback for n not divisible by 4
__global__ __launch_bounds__(256) void edge_kernel1(
    const float*  __restrict__ poses,
    const float2* __restrict__ patch_coords,
    const float*  __restrict__ elev,
    const float2* __restrict__ target,
    const int*    __restrict__ poses_idx,
    const int*    __restrict__ patch_idx,
    float2*       __restrict__ out,
    int n)
{
    int e = blockIdx.x * blockDim.x + threadIdx.x;
    if (e >= n) return;
    float a, b;
    edge_body(patch_coords[patch_idx[e]], elev[patch_idx[e]],
              poses + poses_idx[e] * 7, target[e].x, target[e].y, &a, &b);
    out[e] = make_float2(a, b);
}

extern "C" void kernel_launch(void* const* d_in, const int* in_sizes, int n_in,
                              void* d_out, int out_size, void* d_ws, size_t ws_size,
                              hipStream_t stream) {
    const float*  poses        = (const float*)d_in[0];
    const float2* patch_coords = (const float2*)d_in[1];
    const float*  elev         = (const float*)d_in[2];
    const float2* target       = (const float2*)d_in[3];
    const int*    poses_idx    = (const int*)d_in[4];
    const int*    patch_idx    = (const int*)d_in[5];
    const int n = in_sizes[4];

    if ((n & 3) == 0) {
        const int quarter_n = n / 4;
        edge_kernel4<<<(quarter_n + 255) / 256, 256, 0, stream>>>(
            poses, patch_coords, elev, (const f4*)target,
            (const i4*)poses_idx, (const i4*)patch_idx, (f4*)d_out, quarter_n);
    } else {
        edge_kernel1<<<(n + 255) / 256, 256, 0, stream>>>(
            poses, patch_coords, elev, target, poses_idx, patch_idx,
            (float2*)d_out, n);
    }
}

// Round 7
// 34.667 us; speedup vs baseline: 1.1934x; 1.0228x over previous
//
#include <hip/hip_runtime.h>
#include <math.h>

// Round 7: single kernel, 1 edge/thread (max TLP), pose read as TWO
// overlapping dword-aligned float4 loads from the stride-7 table
// (p[0..3] = t.xyz,qx ; p[3..6] = qx,qy,qz,qw) -- no repack kernel needed.
// Gathers per edge: patch float2 + elev float + 2x pose float4 = 4 divergent
// loads (was 9). f32 everywhere (fp16 table failed: atan2 sensitivity).

typedef float f4u __attribute__((ext_vector_type(4), aligned(4)));

__device__ __forceinline__ float fast_atan2f(float y, float x) {
    float ax = fabsf(x), ay = fabsf(y);
    float mx = fmaxf(ax, ay), mn = fminf(ax, ay);
    float t = mn * __builtin_amdgcn_rcpf(fmaxf(mx, 1e-30f));
    float s = t * t;
    float r = fmaf(s, fmaf(s, fmaf(s, fmaf(s, 0.0208351f, -0.0851330f),
                                   0.1801410f), -0.3302995f), 0.9998660f) * t;
    if (ay > ax) r = 1.5707963267948966f - r;
    if (x < 0.0f) r = 3.14159265358979f - r;
    return y < 0.0f ? -r : r;
}

__global__ __launch_bounds__(256) void edge_kernel(
    const float*  __restrict__ poses,         // [8192*7]
    const float2* __restrict__ patch_coords,  // [NP]
    const float*  __restrict__ elev,          // [NP]
    const float2* __restrict__ target,        // [E]
    const int*    __restrict__ poses_idx,     // [E]
    const int*    __restrict__ patch_idx,     // [E]
    float2*       __restrict__ out,           // [E]
    int n)
{
    int e = blockIdx.x * blockDim.x + threadIdx.x;
    if (e >= n) return;

    const int pi = poses_idx[e];
    const int ki = patch_idx[e];

    // 4 divergent gathers, all issued before any use
    const float2 rt  = patch_coords[ki];
    const float  phi = elev[ki];
    const float* p = poses + pi * 7;
    const f4u A = *(const f4u*)(p);      // t.x t.y t.z qx
    const f4u B = *(const f4u*)(p + 3);  // qx qy qz qw

    float sphi, cphi, st, ct;
    __sincosf(phi,  &sphi, &cphi);
    __sincosf(rt.y, &st,   &ct);
    const float rc = rt.x * cphi;
    const float px = rc * ct, py = rc * st, pz = rt.x * sphi;

    const float tx = A.x, ty = A.y, tz = A.z;
    const float qx = B.x, qy = B.y, qz = B.z, qw = B.w;

    const float ux = qy * pz - qz * py;
    const float uy = qz * px - qx * pz;
    const float uz = qx * py - qy * px;
    const float cx = qy * uz - qz * uy;
    const float cy = qz * ux - qx * uz;
    const float cz = qx * uy - qy * ux;

    const float x = px + 2.0f * (qw * ux + cx) + tx;
    const float y = py + 2.0f * (qw * uy + cy) + ty;
    const float z = pz + 2.0f * (qw * uz + cz) + tz;

    const float2 tg = target[e];
    out[e] = make_float2(sqrtf(x * x + y * y + z * z) - tg.x,
                         fast_atan2f(y, x) - tg.y);
}

extern "C" void kernel_launch(void* const* d_in, const int* in_sizes, int n_in,
                              void* d_out, int out_size, void* d_ws, size_t ws_size,
                              hipStream_t stream) {
    const float*  poses        = (const float*)d_in[0];
    const float2* patch_coords = (const float2*)d_in[1];
    const float*  elev         = (const float*)d_in[2];
    const float2* target       = (const float2*)d_in[3];
    const int*    poses_idx    = (const int*)d_in[4];
    const int*    patch_idx    = (const int*)d_in[5];
    const int n = in_sizes[4];

    edge_kernel<<<(n + 255) / 256, 256, 0, stream>>>(
        poses, patch_coords, elev, target, poses_idx, patch_idx,
        (float2*)d_out, n);
}